// Round 7
// baseline (385.521 us; speedup 1.0000x reference)
//
#include <hip/hip_runtime.h>

#define B_TOTAL 8192
#define T_FULL  100
#define XD      256
#define T0      30
#define TW      70      // time window length (30:100)
#define KS      50      // conv kernel size
#define NT      21      // TW - KS + 1 output positions
#define YOUT    300     // Y_DIM * 50
#define NBF     16      // batches per FC block

// ---------------- named-scalar conv machinery (no arrays, no allocas) -------

#define LOADX(K0) \
  x0 =xp[(K0+ 0)*XD]; x1 =xp[(K0+ 1)*XD]; x2 =xp[(K0+ 2)*XD]; x3 =xp[(K0+ 3)*XD]; x4 =xp[(K0+ 4)*XD]; \
  x5 =xp[(K0+ 5)*XD]; x6 =xp[(K0+ 6)*XD]; x7 =xp[(K0+ 7)*XD]; x8 =xp[(K0+ 8)*XD]; x9 =xp[(K0+ 9)*XD]; \
  x10=xp[(K0+10)*XD]; x11=xp[(K0+11)*XD]; x12=xp[(K0+12)*XD]; x13=xp[(K0+13)*XD]; x14=xp[(K0+14)*XD]; \
  x15=xp[(K0+15)*XD]; x16=xp[(K0+16)*XD]; x17=xp[(K0+17)*XD]; x18=xp[(K0+18)*XD]; x19=xp[(K0+19)*XD]; \
  x20=xp[(K0+20)*XD]; x21=xp[(K0+21)*XD]; x22=xp[(K0+22)*XD]; x23=xp[(K0+23)*XD]; x24=xp[(K0+24)*XD]; \
  x25=xp[(K0+25)*XD]; x26=xp[(K0+26)*XD]; x27=xp[(K0+27)*XD]; x28=xp[(K0+28)*XD]; x29=xp[(K0+29)*XD];

#define LOADW(K0) \
  w0=wtp[(K0+0)*XD]; w1=wtp[(K0+1)*XD]; w2=wtp[(K0+2)*XD]; w3=wtp[(K0+3)*XD]; w4=wtp[(K0+4)*XD]; \
  w5=wtp[(K0+5)*XD]; w6=wtp[(K0+6)*XD]; w7=wtp[(K0+7)*XD]; w8=wtp[(K0+8)*XD]; w9=wtp[(K0+9)*XD];

#define ROW(A, X0,X1,X2,X3,X4,X5,X6,X7,X8,X9) \
  A=fmaf(X0,w0,A); A=fmaf(X1,w1,A); A=fmaf(X2,w2,A); A=fmaf(X3,w3,A); A=fmaf(X4,w4,A); \
  A=fmaf(X5,w5,A); A=fmaf(X6,w6,A); A=fmaf(X7,w7,A); A=fmaf(X8,w8,A); A=fmaf(X9,w9,A);

#define KBLOCK \
  ROW(a0 , x0 ,x1 ,x2 ,x3 ,x4 ,x5 ,x6 ,x7 ,x8 ,x9 ) \
  ROW(a1 , x1 ,x2 ,x3 ,x4 ,x5 ,x6 ,x7 ,x8 ,x9 ,x10) \
  ROW(a2 , x2 ,x3 ,x4 ,x5 ,x6 ,x7 ,x8 ,x9 ,x10,x11) \
  ROW(a3 , x3 ,x4 ,x5 ,x6 ,x7 ,x8 ,x9 ,x10,x11,x12) \
  ROW(a4 , x4 ,x5 ,x6 ,x7 ,x8 ,x9 ,x10,x11,x12,x13) \
  ROW(a5 , x5 ,x6 ,x7 ,x8 ,x9 ,x10,x11,x12,x13,x14) \
  ROW(a6 , x6 ,x7 ,x8 ,x9 ,x10,x11,x12,x13,x14,x15) \
  ROW(a7 , x7 ,x8 ,x9 ,x10,x11,x12,x13,x14,x15,x16) \
  ROW(a8 , x8 ,x9 ,x10,x11,x12,x13,x14,x15,x16,x17) \
  ROW(a9 , x9 ,x10,x11,x12,x13,x14,x15,x16,x17,x18) \
  ROW(a10, x10,x11,x12,x13,x14,x15,x16,x17,x18,x19) \
  ROW(a11, x11,x12,x13,x14,x15,x16,x17,x18,x19,x20) \
  ROW(a12, x12,x13,x14,x15,x16,x17,x18,x19,x20,x21) \
  ROW(a13, x13,x14,x15,x16,x17,x18,x19,x20,x21,x22) \
  ROW(a14, x14,x15,x16,x17,x18,x19,x20,x21,x22,x23) \
  ROW(a15, x15,x16,x17,x18,x19,x20,x21,x22,x23,x24) \
  ROW(a16, x16,x17,x18,x19,x20,x21,x22,x23,x24,x25) \
  ROW(a17, x17,x18,x19,x20,x21,x22,x23,x24,x25,x26) \
  ROW(a18, x18,x19,x20,x21,x22,x23,x24,x25,x26,x27) \
  ROW(a19, x19,x20,x21,x22,x23,x24,x25,x26,x27,x28) \
  ROW(a20, x20,x21,x22,x23,x24,x25,x26,x27,x28,x29)

// ---- kernel 1: transpose conv weights -> wt[k][f] (coalesced conv reads) ---
__global__ __launch_bounds__(256)
void transpose_w(const float* __restrict__ conv_w, float* __restrict__ wt) {
    const int i = blockIdx.x * 256 + threadIdx.x;
    if (i < XD * KS) {                 // conv_w[f][k] -> wt[k][f]
        const int f = i / KS;
        const int k = i - f * KS;
        wt[k * XD + f] = conv_w[i];
    }
}

// ---- kernel 2: depthwise conv + relu + time-max -> feat --------------------
__global__ __launch_bounds__(256, 4)
void conv_kernel(const float* __restrict__ seq, const float* __restrict__ wt,
                 float* __restrict__ feat) {
    const int f = threadIdx.x;
    const int b = blockIdx.x;
    const float* xp  = seq + ((size_t)b * T_FULL + T0) * XD + f;
    const float* wtp = wt + f;

    float a0=0,a1=0,a2=0,a3=0,a4=0,a5=0,a6=0,a7=0,a8=0,a9=0,a10=0,
          a11=0,a12=0,a13=0,a14=0,a15=0,a16=0,a17=0,a18=0,a19=0,a20=0;
    float x0,x1,x2,x3,x4,x5,x6,x7,x8,x9,x10,x11,x12,x13,x14,
          x15,x16,x17,x18,x19,x20,x21,x22,x23,x24,x25,x26,x27,x28,x29;
    float w0,w1,w2,w3,w4,w5,w6,w7,w8,w9;

    LOADW(0);  LOADX(0);  KBLOCK;
    LOADW(10); LOADX(10); KBLOCK;
    LOADW(20); LOADX(20); KBLOCK;
    LOADW(30); LOADX(30); KBLOCK;
    LOADW(40); LOADX(40); KBLOCK;

    float m = 0.f;   // max(relu) == max(0, max_t)
    m=fmaxf(m,a0 ); m=fmaxf(m,a1 ); m=fmaxf(m,a2 ); m=fmaxf(m,a3 ); m=fmaxf(m,a4 );
    m=fmaxf(m,a5 ); m=fmaxf(m,a6 ); m=fmaxf(m,a7 ); m=fmaxf(m,a8 ); m=fmaxf(m,a9 );
    m=fmaxf(m,a10); m=fmaxf(m,a11); m=fmaxf(m,a12); m=fmaxf(m,a13); m=fmaxf(m,a14);
    m=fmaxf(m,a15); m=fmaxf(m,a16); m=fmaxf(m,a17); m=fmaxf(m,a18); m=fmaxf(m,a19);
    m=fmaxf(m,a20);
    feat[(size_t)b * XD + f] = m;
}

// ---- kernel 3: FC, 16 batches per block, feat staged in LDS ----------------
// fc_w stays in its native [o][in] layout: each thread reads one contiguous
// 1 KB row via float4; the block's 256 rows are contiguous in memory and
// L1/L2-resident. fc_w L2 traffic: 512 blocks x 307 KB = 157 MB (was 2.95 GB).
__global__ __launch_bounds__(256, 4)
void fc_kernel(const float* __restrict__ feat, const float* __restrict__ fc_w,
               float* __restrict__ out) {
    __shared__ float fv[NBF][XD];
    const int b0 = blockIdx.x * NBF;

    // cooperative float4 load of 16 feat rows (16 KB)
    const float4* fsrc = reinterpret_cast<const float4*>(feat + (size_t)b0 * XD);
    float4* fdst = reinterpret_cast<float4*>(&fv[0][0]);
    for (int i = threadIdx.x; i < NBF * XD / 4; i += 256) fdst[i] = fsrc[i];
    __syncthreads();

    for (int idx = threadIdx.x; idx < NBF * YOUT; idx += 256) {
        const int nb = idx / YOUT;
        const int o  = idx - nb * YOUT;
        const float4* wrow = reinterpret_cast<const float4*>(fc_w + (size_t)o * XD);
        float c0 = 0.f, c1 = 0.f, c2 = 0.f, c3 = 0.f;
#pragma unroll
        for (int q = 0; q < XD / 4; ++q) {
            const float4 wv = wrow[q];
            const float4 xq = *reinterpret_cast<const float4*>(&fv[nb][4 * q]); // LDS broadcast
            c0 = fmaf(wv.x, xq.x, c0);
            c1 = fmaf(wv.y, xq.y, c1);
            c2 = fmaf(wv.z, xq.z, c2);
            c3 = fmaf(wv.w, xq.w, c3);
        }
        out[(size_t)(b0 + nb) * YOUT + o] = (c0 + c1) + (c2 + c3);
    }
}

extern "C" void kernel_launch(void* const* d_in, const int* in_sizes, int n_in,
                              void* d_out, int out_size, void* d_ws, size_t ws_size,
                              hipStream_t stream) {
    const float* seq    = (const float*)d_in[0];
    const float* conv_w = (const float*)d_in[1];
    const float* fc_w   = (const float*)d_in[2];
    float*       out    = (float*)d_out;

    float* wt   = (float*)d_ws;          // [50][256]  = 51.2 KB
    float* feat = wt + XD * KS;          // [8192][256] = 8.39 MB

    transpose_w<<<dim3((XD * KS + 255) / 256), dim3(256), 0, stream>>>(conv_w, wt);
    conv_kernel<<<dim3(B_TOTAL), dim3(256), 0, stream>>>(seq, wt, feat);
    fc_kernel<<<dim3(B_TOTAL / NBF), dim3(256), 0, stream>>>(feat, fc_w, out);
}

// Round 8
// 183.680 us; speedup vs baseline: 2.0989x; 2.0989x over previous
//
#include <hip/hip_runtime.h>

#define B_TOTAL 8192
#define T_FULL  100
#define XD      256
#define T0      30
#define TW      70      // time window length (30:100)
#define KS      50      // conv kernel size
#define NT      21      // TW - KS + 1 output positions
#define YOUT    300     // Y_DIM * 50
#define FC_NB   16      // batches per FC block

// ---------------- named-scalar conv machinery (no arrays, no allocas) -------

#define LOADX(K0) \
  x0 =xp[(K0+ 0)*XD]; x1 =xp[(K0+ 1)*XD]; x2 =xp[(K0+ 2)*XD]; x3 =xp[(K0+ 3)*XD]; x4 =xp[(K0+ 4)*XD]; \
  x5 =xp[(K0+ 5)*XD]; x6 =xp[(K0+ 6)*XD]; x7 =xp[(K0+ 7)*XD]; x8 =xp[(K0+ 8)*XD]; x9 =xp[(K0+ 9)*XD]; \
  x10=xp[(K0+10)*XD]; x11=xp[(K0+11)*XD]; x12=xp[(K0+12)*XD]; x13=xp[(K0+13)*XD]; x14=xp[(K0+14)*XD]; \
  x15=xp[(K0+15)*XD]; x16=xp[(K0+16)*XD]; x17=xp[(K0+17)*XD]; x18=xp[(K0+18)*XD]; x19=xp[(K0+19)*XD]; \
  x20=xp[(K0+20)*XD]; x21=xp[(K0+21)*XD]; x22=xp[(K0+22)*XD]; x23=xp[(K0+23)*XD]; x24=xp[(K0+24)*XD]; \
  x25=xp[(K0+25)*XD]; x26=xp[(K0+26)*XD]; x27=xp[(K0+27)*XD]; x28=xp[(K0+28)*XD]; x29=xp[(K0+29)*XD];

#define LOADW(K0) \
  w0=wtp[(K0+0)*XD]; w1=wtp[(K0+1)*XD]; w2=wtp[(K0+2)*XD]; w3=wtp[(K0+3)*XD]; w4=wtp[(K0+4)*XD]; \
  w5=wtp[(K0+5)*XD]; w6=wtp[(K0+6)*XD]; w7=wtp[(K0+7)*XD]; w8=wtp[(K0+8)*XD]; w9=wtp[(K0+9)*XD];

#define ROW(A, X0,X1,X2,X3,X4,X5,X6,X7,X8,X9) \
  A=fmaf(X0,w0,A); A=fmaf(X1,w1,A); A=fmaf(X2,w2,A); A=fmaf(X3,w3,A); A=fmaf(X4,w4,A); \
  A=fmaf(X5,w5,A); A=fmaf(X6,w6,A); A=fmaf(X7,w7,A); A=fmaf(X8,w8,A); A=fmaf(X9,w9,A);

#define KBLOCK \
  ROW(a0 , x0 ,x1 ,x2 ,x3 ,x4 ,x5 ,x6 ,x7 ,x8 ,x9 ) \
  ROW(a1 , x1 ,x2 ,x3 ,x4 ,x5 ,x6 ,x7 ,x8 ,x9 ,x10) \
  ROW(a2 , x2 ,x3 ,x4 ,x5 ,x6 ,x7 ,x8 ,x9 ,x10,x11) \
  ROW(a3 , x3 ,x4 ,x5 ,x6 ,x7 ,x8 ,x9 ,x10,x11,x12) \
  ROW(a4 , x4 ,x5 ,x6 ,x7 ,x8 ,x9 ,x10,x11,x12,x13) \
  ROW(a5 , x5 ,x6 ,x7 ,x8 ,x9 ,x10,x11,x12,x13,x14) \
  ROW(a6 , x6 ,x7 ,x8 ,x9 ,x10,x11,x12,x13,x14,x15) \
  ROW(a7 , x7 ,x8 ,x9 ,x10,x11,x12,x13,x14,x15,x16) \
  ROW(a8 , x8 ,x9 ,x10,x11,x12,x13,x14,x15,x16,x17) \
  ROW(a9 , x9 ,x10,x11,x12,x13,x14,x15,x16,x17,x18) \
  ROW(a10, x10,x11,x12,x13,x14,x15,x16,x17,x18,x19) \
  ROW(a11, x11,x12,x13,x14,x15,x16,x17,x18,x19,x20) \
  ROW(a12, x12,x13,x14,x15,x16,x17,x18,x19,x20,x21) \
  ROW(a13, x13,x14,x15,x16,x17,x18,x19,x20,x21,x22) \
  ROW(a14, x14,x15,x16,x17,x18,x19,x20,x21,x22,x23) \
  ROW(a15, x15,x16,x17,x18,x19,x20,x21,x22,x23,x24) \
  ROW(a16, x16,x17,x18,x19,x20,x21,x22,x23,x24,x25) \
  ROW(a17, x17,x18,x19,x20,x21,x22,x23,x24,x25,x26) \
  ROW(a18, x18,x19,x20,x21,x22,x23,x24,x25,x26,x27) \
  ROW(a19, x19,x20,x21,x22,x23,x24,x25,x26,x27,x28) \
  ROW(a20, x20,x21,x22,x23,x24,x25,x26,x27,x28,x29)

// ---- kernel 1: weight transposes ------------------------------------------
// conv_w[f][k] -> wt[k][f]  (coalesced conv reads)
// fc_w[o][q]   -> fct[q][o] (coalesced FC reads: lane = o)
__global__ __launch_bounds__(256)
void transpose_w(const float* __restrict__ conv_w, const float* __restrict__ fc_w,
                 float* __restrict__ wt, float* __restrict__ fct) {
    const int i = blockIdx.x * 256 + threadIdx.x;
    if (i < XD * KS) {
        const int f = i / KS;
        const int k = i - f * KS;
        wt[k * XD + f] = conv_w[i];
    }
    if (i < YOUT * XD) {
        const int o = i >> 8;          // fc_w row
        const int q = i & 255;         // fc_w col (coalesced read)
        fct[q * YOUT + o] = fc_w[i];
    }
}

// ---- kernel 2: depthwise conv + relu + time-max -> feat (round-6 verbatim) -
__global__ __launch_bounds__(256, 4)
void conv_kernel(const float* __restrict__ seq, const float* __restrict__ wt,
                 float* __restrict__ feat) {
    const int f = threadIdx.x;
    const int b = blockIdx.x;
    const float* xp  = seq + ((size_t)b * T_FULL + T0) * XD + f;
    const float* wtp = wt + f;

    float a0=0,a1=0,a2=0,a3=0,a4=0,a5=0,a6=0,a7=0,a8=0,a9=0,a10=0,
          a11=0,a12=0,a13=0,a14=0,a15=0,a16=0,a17=0,a18=0,a19=0,a20=0;
    float x0,x1,x2,x3,x4,x5,x6,x7,x8,x9,x10,x11,x12,x13,x14,
          x15,x16,x17,x18,x19,x20,x21,x22,x23,x24,x25,x26,x27,x28,x29;
    float w0,w1,w2,w3,w4,w5,w6,w7,w8,w9;

    LOADW(0);  LOADX(0);  KBLOCK;
    LOADW(10); LOADX(10); KBLOCK;
    LOADW(20); LOADX(20); KBLOCK;
    LOADW(30); LOADX(30); KBLOCK;
    LOADW(40); LOADX(40); KBLOCK;

    float m = 0.f;   // max(relu) == max(0, max_t)
    m=fmaxf(m,a0 ); m=fmaxf(m,a1 ); m=fmaxf(m,a2 ); m=fmaxf(m,a3 ); m=fmaxf(m,a4 );
    m=fmaxf(m,a5 ); m=fmaxf(m,a6 ); m=fmaxf(m,a7 ); m=fmaxf(m,a8 ); m=fmaxf(m,a9 );
    m=fmaxf(m,a10); m=fmaxf(m,a11); m=fmaxf(m,a12); m=fmaxf(m,a13); m=fmaxf(m,a14);
    m=fmaxf(m,a15); m=fmaxf(m,a16); m=fmaxf(m,a17); m=fmaxf(m,a18); m=fmaxf(m,a19);
    m=fmaxf(m,a20);
    feat[(size_t)b * XD + f] = m;
}

// ---- kernel 3: FC ----------------------------------------------------------
// Block = 16 batches x 300 outputs. lane = o -> fct[q][o] reads coalesced.
// feat[(b0+nb)*XD+q] is block-uniform -> scalar loads (SGPR broadcast), so
// there is no per-lane broadcast traffic and no LDS at all.
#define FCSTEP(C, NB_) C = fmaf(wv, fb[(NB_) * XD + q], C);

__global__ __launch_bounds__(320, 2)
void fc_kernel(const float* __restrict__ feat, const float* __restrict__ fct,
               float* __restrict__ out) {
    const int o  = threadIdx.x;
    const int b0 = blockIdx.x * FC_NB;
    if (o >= YOUT) return;

    const float* fb = feat + (size_t)b0 * XD;

    float c0=0,c1=0,c2=0,c3=0,c4=0,c5=0,c6=0,c7=0,
          c8=0,c9=0,c10=0,c11=0,c12=0,c13=0,c14=0,c15=0;

#pragma unroll 2
    for (int q = 0; q < XD; ++q) {
        const float wv = fct[q * YOUT + o];   // coalesced across lanes
        FCSTEP(c0 , 0)  FCSTEP(c1 , 1)  FCSTEP(c2 , 2)  FCSTEP(c3 , 3)
        FCSTEP(c4 , 4)  FCSTEP(c5 , 5)  FCSTEP(c6 , 6)  FCSTEP(c7 , 7)
        FCSTEP(c8 , 8)  FCSTEP(c9 , 9)  FCSTEP(c10,10)  FCSTEP(c11,11)
        FCSTEP(c12,12)  FCSTEP(c13,13)  FCSTEP(c14,14)  FCSTEP(c15,15)
    }

    out[(size_t)(b0 +  0) * YOUT + o] = c0;
    out[(size_t)(b0 +  1) * YOUT + o] = c1;
    out[(size_t)(b0 +  2) * YOUT + o] = c2;
    out[(size_t)(b0 +  3) * YOUT + o] = c3;
    out[(size_t)(b0 +  4) * YOUT + o] = c4;
    out[(size_t)(b0 +  5) * YOUT + o] = c5;
    out[(size_t)(b0 +  6) * YOUT + o] = c6;
    out[(size_t)(b0 +  7) * YOUT + o] = c7;
    out[(size_t)(b0 +  8) * YOUT + o] = c8;
    out[(size_t)(b0 +  9) * YOUT + o] = c9;
    out[(size_t)(b0 + 10) * YOUT + o] = c10;
    out[(size_t)(b0 + 11) * YOUT + o] = c11;
    out[(size_t)(b0 + 12) * YOUT + o] = c12;
    out[(size_t)(b0 + 13) * YOUT + o] = c13;
    out[(size_t)(b0 + 14) * YOUT + o] = c14;
    out[(size_t)(b0 + 15) * YOUT + o] = c15;
}

extern "C" void kernel_launch(void* const* d_in, const int* in_sizes, int n_in,
                              void* d_out, int out_size, void* d_ws, size_t ws_size,
                              hipStream_t stream) {
    const float* seq    = (const float*)d_in[0];
    const float* conv_w = (const float*)d_in[1];
    const float* fc_w   = (const float*)d_in[2];
    float*       out    = (float*)d_out;

    float* wt   = (float*)d_ws;          // [50][256]   = 51.2 KB
    float* fct  = wt  + XD * KS;         // [256][300]  = 307.2 KB
    float* feat = fct + XD * YOUT;       // [8192][256] = 8.39 MB

    transpose_w<<<dim3((YOUT * XD + 255) / 256), dim3(256), 0, stream>>>(conv_w, fc_w, wt, fct);
    conv_kernel<<<dim3(B_TOTAL), dim3(256), 0, stream>>>(seq, wt, feat);
    fc_kernel<<<dim3(B_TOTAL / FC_NB), dim3(320), 0, stream>>>(feat, fct, out);
}